// Round 5
// baseline (1785.672 us; speedup 1.0000x reference)
//
#include <hip/hip_runtime.h>
#include <cfloat>
#include <climits>

// ---------------- problem constants ----------------
#define B_SZ   8
#define C2     128
#define C3     256
#define H2     28
#define W2     28
#define H3     14
#define W3     14
#define CDIM   384
#define N_EMB  (B_SZ*H2*W2)      // 6272 = 98 tiles of 64
#define M_BANK 30000
#define MP2    30208             // padded to multiple of 256
#define NT256  (MP2/256)         // 118 m-tiles of 256
#define IMGSZ  224
#define GY     16                // M-split slices (XCD-pinned: slice y -> XCD y%8)
#define TOPK   9
#define SPLIT  32                // per-b segments for top-k
#define LDSROW 392               // 384 + 8 bf16 pad (784B rows -> balanced LDS quads)

typedef __attribute__((ext_vector_type(8))) short short8v;   // bf16x8 bits (4 VGPR)
typedef __attribute__((ext_vector_type(4))) float f32x4;

// ---------------- bf16 split helpers ----------------
__device__ __forceinline__ ushort f2bf(float x) {
  union { float f; unsigned u; } a; a.f = x;
  const unsigned r = a.u + 0x7fffu + ((a.u >> 16) & 1u);   // RNE
  return (ushort)(r >> 16);
}
__device__ __forceinline__ float bf2f(ushort b) {
  union { float f; unsigned u; } a; a.u = ((unsigned)b) << 16;
  return a.f;
}

// ---------------- embedding build ----------------
__global__ __launch_bounds__(256) void pool2_kernel(const float* __restrict__ feat2,
                                                    float* __restrict__ embT) {
  const int bc = blockIdx.x;            // b*128+c
  const int b = bc >> 7, c = bc & 127;
  __shared__ float plane[H2*W2];
  const float* src = feat2 + (size_t)bc * (H2*W2);
  for (int i = threadIdx.x; i < H2*W2; i += 256) plane[i] = src[i];
  __syncthreads();
  for (int i = threadIdx.x; i < H2*W2; i += 256) {
    const int h = i / W2, w = i % W2;
    float s = 0.f;
    #pragma unroll
    for (int dh = -1; dh <= 1; ++dh)
      #pragma unroll
      for (int dw = -1; dw <= 1; ++dw) {
        const int hh = h + dh, ww = w + dw;
        if (hh >= 0 && hh < H2 && ww >= 0 && ww < W2) s += plane[hh*W2 + ww];
      }
    embT[(size_t)c * N_EMB + (size_t)b * (H2*W2) + i] = s * (1.0f/9.0f);
  }
}

__global__ __launch_bounds__(256) void pool3up_kernel(const float* __restrict__ feat3,
                                                      float* __restrict__ embT) {
  const int bc = blockIdx.x;            // b*256+c
  const int b = bc >> 8, c = bc & 255;
  __shared__ float plane[H3*W3];
  __shared__ float pooled[H3*W3];
  const float* src = feat3 + (size_t)bc * (H3*W3);
  for (int i = threadIdx.x; i < H3*W3; i += 256) plane[i] = src[i];
  __syncthreads();
  for (int i = threadIdx.x; i < H3*W3; i += 256) {
    const int h = i / W3, w = i % W3;
    float s = 0.f;
    #pragma unroll
    for (int dh = -1; dh <= 1; ++dh)
      #pragma unroll
      for (int dw = -1; dw <= 1; ++dw) {
        const int hh = h + dh, ww = w + dw;
        if (hh >= 0 && hh < H3 && ww >= 0 && ww < W3) s += plane[hh*W3 + ww];
      }
    pooled[i] = s * (1.0f/9.0f);
  }
  __syncthreads();
  for (int i = threadIdx.x; i < H2*W2; i += 256) {
    const int h = i / W2, w = i % W2;
    const float sy = h*0.5f - 0.25f, sx = w*0.5f - 0.25f;
    const int y0 = (int)floorf(sy), x0 = (int)floorf(sx);
    const float fy = sy - y0, fx = sx - x0;
    const int y0c = min(max(y0, 0), H3-1),   y1c = min(max(y0+1, 0), H3-1);
    const int x0c = min(max(x0, 0), W3-1),   x1c = min(max(x0+1, 0), W3-1);
    const float v =
        (1.f-fy)*((1.f-fx)*pooled[y0c*W3+x0c] + fx*pooled[y0c*W3+x1c]) +
             fy *((1.f-fx)*pooled[y1c*W3+x0c] + fx*pooled[y1c*W3+x1c]);
    embT[(size_t)(C2 + c) * N_EMB + (size_t)b * (H2*W2) + i] = v;
  }
}

// transpose+convert: embT[C][N] f32 -> ehi/elo [N][C] bf16
__global__ __launch_bounds__(256) void embconv(const float* __restrict__ embT,
                                               ushort* __restrict__ eh,
                                               ushort* __restrict__ el) {
  __shared__ float tile[32][33];
  const int tid = threadIdx.x;
  const int n0 = blockIdx.x*32, c0 = blockIdx.y*32;
  #pragma unroll
  for (int p = 0; p < 4; ++p) {
    const int c = p*8 + (tid >> 5);
    const int n = tid & 31;
    tile[n][c] = embT[(size_t)(c0 + c)*N_EMB + n0 + n];
  }
  __syncthreads();
  const int nr = tid >> 3, cq = (tid & 7) << 2;
  ushort4 h, l;
  float v0 = tile[nr][cq+0], v1 = tile[nr][cq+1], v2 = tile[nr][cq+2], v3 = tile[nr][cq+3];
  h.x = f2bf(v0); h.y = f2bf(v1); h.z = f2bf(v2); h.w = f2bf(v3);
  l.x = f2bf(v0 - bf2f(h.x)); l.y = f2bf(v1 - bf2f(h.y));
  l.z = f2bf(v2 - bf2f(h.z)); l.w = f2bf(v3 - bf2f(h.w));
  *(ushort4*)&eh[(size_t)(n0+nr)*CDIM + c0 + cq] = h;
  *(ushort4*)&el[(size_t)(n0+nr)*CDIM + c0 + cq] = l;
}

// bank f32 [30000][384] -> bh/bl bf16 [MP2][384] (pad rows zero)
__global__ __launch_bounds__(256) void conv_bank(const float* __restrict__ bank,
                                                 ushort* __restrict__ bh,
                                                 ushort* __restrict__ bl) {
  const size_t i = (size_t)blockIdx.x*256 + threadIdx.x;   // one float4 per thread
  if (i >= (size_t)MP2*CDIM/4) return;
  const size_t e = i*4;
  const int row = (int)(e / CDIM);
  ushort4 h = {0,0,0,0}, l = {0,0,0,0};
  if (row < M_BANK) {
    const float4 v = *(const float4*)&bank[e];
    h.x = f2bf(v.x); h.y = f2bf(v.y); h.z = f2bf(v.z); h.w = f2bf(v.w);
    l.x = f2bf(v.x - bf2f(h.x)); l.y = f2bf(v.y - bf2f(h.y));
    l.z = f2bf(v.z - bf2f(h.z)); l.w = f2bf(v.w - bf2f(h.w));
  }
  *(ushort4*)&bh[e] = h;
  *(ushort4*)&bl[e] = l;
}

// ---------------- norms ----------------
__global__ void xn_kernel(const float* __restrict__ embT, float* __restrict__ xn) {
  const int n = blockIdx.x*256 + threadIdx.x;
  if (n >= N_EMB) return;
  float s = 0.f;
  for (int c = 0; c < CDIM; ++c) {
    const float v = embT[(size_t)c * N_EMB + n];
    s = fmaf(v, v, s);
  }
  xn[n] = s;
}

__global__ void yn_kernel(const float* __restrict__ bank, float* __restrict__ yn) {
  const int wave = threadIdx.x >> 6, lane = threadIdx.x & 63;
  const int m = blockIdx.x*4 + wave;
  if (m >= MP2) return;
  if (m >= M_BANK) { if (lane == 0) yn[m] = 1e30f; return; }
  const float* row = bank + (size_t)m * CDIM;
  float s = 0.f;
  #pragma unroll
  for (int j = 0; j < CDIM/64; ++j) {
    const float v = row[lane + j*64];
    s = fmaf(v, v, s);
  }
  #pragma unroll
  for (int sh = 32; sh > 0; sh >>= 1) s += __shfl_down(s, sh);
  if (lane == 0) yn[m] = s;
}

// ---------------- fused distance GEMM (bf16-split MFMA) + min/argmin ----------------
// XCD-pinned: flat%8 = XCD (HW round-robin); XCD k owns slices y=k and y=k+8.
// Slice tile counts: y<6 -> 8 m-tiles, else 7 (NT256=118 total).
__global__ __launch_bounds__(512) void distmin_mfma(
    const ushort* __restrict__ ehi, const ushort* __restrict__ elo,
    const ushort* __restrict__ bhi, const ushort* __restrict__ blo,
    const float* __restrict__ xn,   const float* __restrict__ yn,
    float* __restrict__ pmin, int* __restrict__ parg)
{
  __shared__ ushort eshi[64*LDSROW];
  __shared__ ushort eslo[64*LDSROW];
  __shared__ float rv[8*64];
  __shared__ int   ri[8*64];

  const int tid = threadIdx.x;
  const int wave = tid >> 6, lane = tid & 63;
  const int lg = lane >> 4, lr = lane & 15;

  // ---- XCD-pinning swizzle (bijective over 98x16) ----
  const int flat = blockIdx.y * 98 + blockIdx.x;
  const int xcd  = flat & 7;
  const int j    = flat >> 3;          // 0..195
  const int half = (j >= 98) ? 1 : 0;
  const int xt   = j - half*98;        // 0..97
  const int yt   = xcd + half*8;       // 0..15
  const int n0   = xt * 64;
  const int mt0  = (yt < 6) ? yt*8 : 48 + (yt-6)*7;
  const int mt1  = mt0 + ((yt < 6) ? 8 : 7);

  // stage emb tile (hi+lo), full K, row-padded
  for (int idx = tid; idx < 64*48; idx += 512) {
    const int r = idx / 48, c8 = (idx % 48) * 8;
    *(short8v*)&eshi[r*LDSROW + c8] = *(const short8v*)&ehi[(size_t)(n0 + r)*CDIM + c8];
    *(short8v*)&eslo[r*LDSROW + c8] = *(const short8v*)&elo[(size_t)(n0 + r)*CDIM + c8];
  }
  __syncthreads();

  float bestv[4]; int besti[4];
  #pragma unroll
  for (int t = 0; t < 4; ++t) { bestv[t] = FLT_MAX; besti[t] = INT_MAX; }

  for (int mt = mt0; mt < mt1; ++mt) {
    const int mbase = mt*256 + wave*32;
    f32x4 acc[2][4];
    #pragma unroll
    for (int f = 0; f < 2; ++f)
      #pragma unroll
      for (int t = 0; t < 4; ++t) acc[f][t] = (f32x4){0.f, 0.f, 0.f, 0.f};

    const ushort* a0h = bhi + (size_t)(mbase      + lr)*CDIM + lg*8;
    const ushort* a0l = blo + (size_t)(mbase      + lr)*CDIM + lg*8;
    const ushort* a1h = bhi + (size_t)(mbase + 16 + lr)*CDIM + lg*8;
    const ushort* a1l = blo + (size_t)(mbase + 16 + lr)*CDIM + lg*8;
    const int ebase = lr*LDSROW + lg*8;

    #pragma unroll
    for (int kc = 0; kc < 12; ++kc) {
      const int k0 = kc*32;
      const short8v va0h = *(const short8v*)&a0h[k0];
      const short8v va0l = *(const short8v*)&a0l[k0];
      const short8v va1h = *(const short8v*)&a1h[k0];
      const short8v va1l = *(const short8v*)&a1l[k0];
      #pragma unroll
      for (int t = 0; t < 4; ++t) {
        const short8v vbh = *(const short8v*)&eshi[ebase + t*16*LDSROW + k0];
        const short8v vbl = *(const short8v*)&eslo[ebase + t*16*LDSROW + k0];
        acc[0][t] = __builtin_amdgcn_mfma_f32_16x16x32_bf16(va0h, vbh, acc[0][t], 0, 0, 0);
        acc[0][t] = __builtin_amdgcn_mfma_f32_16x16x32_bf16(va0h, vbl, acc[0][t], 0, 0, 0);
        acc[0][t] = __builtin_amdgcn_mfma_f32_16x16x32_bf16(va0l, vbh, acc[0][t], 0, 0, 0);
        acc[1][t] = __builtin_amdgcn_mfma_f32_16x16x32_bf16(va1h, vbh, acc[1][t], 0, 0, 0);
        acc[1][t] = __builtin_amdgcn_mfma_f32_16x16x32_bf16(va1h, vbl, acc[1][t], 0, 0, 0);
        acc[1][t] = __builtin_amdgcn_mfma_f32_16x16x32_bf16(va1l, vbh, acc[1][t], 0, 0, 0);
      }
    }
    // epilogue: d2' = yn - 2*dot (xn added at write; same argmin)
    const int mrow = mbase + lg*4;
    #pragma unroll
    for (int f = 0; f < 2; ++f) {
      const float4 y4 = *(const float4*)&yn[mrow + f*16];
      const float yv[4] = {y4.x, y4.y, y4.z, y4.w};
      #pragma unroll
      for (int r = 0; r < 4; ++r) {
        const int m = mrow + f*16 + r;
        #pragma unroll
        for (int t = 0; t < 4; ++t) {
          const float d = yv[r] - 2.0f*acc[f][t][r];
          if (d < bestv[t]) { bestv[t] = d; besti[t] = m; }
        }
      }
    }
  }

  // cross-lane reduce (lanes holding same n: xor 16, 32), first-index ties
  #pragma unroll
  for (int t = 0; t < 4; ++t) {
    float v = bestv[t]; int bi = besti[t];
    #pragma unroll
    for (int off = 16; off < 64; off <<= 1) {
      const float ov = __shfl_xor(v, off);
      const int   oi = __shfl_xor(bi, off);
      if (ov < v || (ov == v && oi < bi)) { v = ov; bi = oi; }
    }
    if (lg == 0) { rv[wave*64 + t*16 + lr] = v; ri[wave*64 + t*16 + lr] = bi; }
  }
  __syncthreads();
  if (tid < 64) {
    float bv = rv[tid]; int bi = ri[tid];
    #pragma unroll
    for (int w = 1; w < 8; ++w) {
      const float v = rv[w*64 + tid]; const int ix = ri[w*64 + tid];
      if (v < bv || (v == bv && ix < bi)) { bv = v; bi = ix; }
    }
    pmin[(size_t)yt*N_EMB + n0 + tid] = xn[n0 + tid] + bv;
    parg[(size_t)yt*N_EMB + n0 + tid] = bi;
  }
}

// combine GY chunks -> patch score (sqrt) + location
__global__ void reduce_chunks(const float* __restrict__ pmin, const int* __restrict__ parg,
                              float* __restrict__ pscore, int* __restrict__ ploc) {
  const int n = blockIdx.x*256 + threadIdx.x;
  if (n >= N_EMB) return;
  float bv = pmin[n]; int bi = parg[n];
  for (int y = 1; y < GY; ++y) {
    const float v = pmin[(size_t)y*N_EMB + n];
    const int ix = parg[(size_t)y*N_EMB + n];
    if (v < bv || (v == bv && ix < bi)) { bv = v; bi = ix; }
  }
  pscore[n] = sqrtf(fmaxf(bv, 0.f));
  ploc[n] = bi;
}

// ---------------- per-batch argmax + gathers ----------------
__global__ __launch_bounds__(256) void perb_argmax(
    const float* __restrict__ pscore, const int* __restrict__ ploc,
    const float* __restrict__ embT,   const float* __restrict__ xn,
    float* __restrict__ scoreB, int* __restrict__ nnidx,
    float* __restrict__ maxfeat, float* __restrict__ mfnorm)
{
  const int b = blockIdx.x, tid = threadIdx.x;
  __shared__ float sv[256]; __shared__ int si[256];
  float bv = -FLT_MAX; int bi = INT_MAX;
  for (int p = tid; p < H2*W2; p += 256) {
    const float v = pscore[b*(H2*W2) + p];
    if (v > bv) { bv = v; bi = p; }
  }
  sv[tid] = bv; si[tid] = bi;
  __syncthreads();
  for (int s = 128; s > 0; s >>= 1) {
    if (tid < s) {
      if (sv[tid+s] > sv[tid] || (sv[tid+s] == sv[tid] && si[tid+s] < si[tid])) {
        sv[tid] = sv[tid+s]; si[tid] = si[tid+s];
      }
    }
    __syncthreads();
  }
  const int n = b*(H2*W2) + si[0];
  if (tid == 0) { scoreB[b] = sv[0]; nnidx[b] = ploc[n]; mfnorm[b] = xn[n]; }
  for (int c = tid; c < CDIM; c += 256) maxfeat[b*CDIM + c] = embT[(size_t)c*N_EMB + n];
}

// ---------------- per-batch 9-NN of nn_sample: 8 batches fused per segment ----------------
// One block per segment; streams each bank row ONCE, dots against all 8 nn vectors.
__global__ __launch_bounds__(512) void topk_partial(
    const float* __restrict__ bank, const float* __restrict__ yn,
    const int* __restrict__ nnidx, float* __restrict__ candv, int* __restrict__ candi)
{
  const int seg = blockIdx.x, tid = threadIdx.x;
  __shared__ float nnf[B_SZ*CDIM];        // 12 KB
  __shared__ float d2s[B_SZ][1024];       // 32 KB
  __shared__ float nrm[B_SZ];
  for (int i = tid; i < B_SZ*CDIM; i += 512) {
    const int b = i / CDIM, c = i % CDIM;
    nnf[i] = bank[(size_t)nnidx[b]*CDIM + c];
  }
  if (tid < B_SZ) nrm[tid] = yn[nnidx[tid]];
  __syncthreads();
  const int per = (M_BANK + SPLIT - 1) / SPLIT;   // 938
  const int mlo = seg * per;
  const int mhi = min(mlo + per, M_BANK);
  #pragma unroll
  for (int i = 0; i < 2; ++i) {
    const int p = i*512 + tid;
    const int m = mlo + p;
    if (m < mhi) {
      const float* row = bank + (size_t)m*CDIM;
      float dot[B_SZ];
      #pragma unroll
      for (int b = 0; b < B_SZ; ++b) dot[b] = 0.f;
      for (int c = 0; c < CDIM; c += 4) {
        const float4 r4 = *(const float4*)&row[c];
        #pragma unroll
        for (int b = 0; b < B_SZ; ++b) {
          dot[b] = fmaf(r4.x, nnf[b*CDIM+c+0], dot[b]);
          dot[b] = fmaf(r4.y, nnf[b*CDIM+c+1], dot[b]);
          dot[b] = fmaf(r4.z, nnf[b*CDIM+c+2], dot[b]);
          dot[b] = fmaf(r4.w, nnf[b*CDIM+c+3], dot[b]);
        }
      }
      const float ym = yn[m];
      #pragma unroll
      for (int b = 0; b < B_SZ; ++b) d2s[b][p] = nrm[b] - 2.f*dot[b] + ym;
    } else {
      #pragma unroll
      for (int b = 0; b < B_SZ; ++b) d2s[b][p] = FLT_MAX;
    }
  }
  __syncthreads();
  // wave w owns batch b=w: 9 rounds of lex-min over its own 1024 entries
  const int b = tid >> 6, lane = tid & 63;
  for (int r = 0; r < TOPK; ++r) {
    float bv = FLT_MAX; int bp = INT_MAX;
    #pragma unroll
    for (int s = 0; s < 16; ++s) {
      const int p = lane + s*64;
      const float v = d2s[b][p];
      if (v < bv || (v == bv && p < bp)) { bv = v; bp = p; }
    }
    #pragma unroll
    for (int off = 32; off > 0; off >>= 1) {
      const float ov = __shfl_down(bv, off);
      const int   op = __shfl_down(bp, off);
      if (ov < bv || (ov == bv && op < bp)) { bv = ov; bp = op; }
    }
    if (lane == 0) {
      candv[((size_t)b*SPLIT + seg)*TOPK + r] = bv;
      candi[((size_t)b*SPLIT + seg)*TOPK + r] = mlo + bp;
      d2s[b][bp] = FLT_MAX;
    }
    __syncthreads();
  }
}

// ---------------- merge candidates, compute pred_score ----------------
__global__ __launch_bounds__(320) void final_score(
    const float* __restrict__ bank, const float* __restrict__ yn,
    const float* __restrict__ candv, const int* __restrict__ candi,
    const float* __restrict__ maxfeat, const float* __restrict__ mfnorm,
    const float* __restrict__ scoreB, float* __restrict__ outp)
{
  const int b = blockIdx.x, tid = threadIdx.x;
  __shared__ float av[SPLIT*TOPK]; __shared__ int ai[SPLIT*TOPK];
  __shared__ int sup[TOPK];
  __shared__ float dist2[TOPK];
  if (tid < SPLIT*TOPK) {
    av[tid] = candv[(size_t)b*SPLIT*TOPK + tid];
    ai[tid] = candi[(size_t)b*SPLIT*TOPK + tid];
  }
  __syncthreads();
  if (tid == 0) {
    for (int r = 0; r < TOPK; ++r) {
      float bv = FLT_MAX; int bi = INT_MAX; int bp = -1;
      for (int p = 0; p < SPLIT*TOPK; ++p) {
        if (av[p] < bv || (av[p] == bv && ai[p] < bi)) { bv = av[p]; bi = ai[p]; bp = p; }
      }
      sup[r] = bi; av[bp] = FLT_MAX;
    }
  }
  __syncthreads();
  if (tid < TOPK*32) {
    const int j = tid >> 5, l = tid & 31;
    const float* row = bank + (size_t)sup[j]*CDIM;
    const float* mf  = maxfeat + b*CDIM;
    float p = 0.f;
    for (int c = l; c < CDIM; c += 32) p = fmaf(row[c], mf[c], p);
    #pragma unroll
    for (int s = 16; s > 0; s >>= 1) p += __shfl_down(p, s, 32);
    if (l == 0) dist2[j] = mfnorm[b] - 2.f*p + yn[sup[j]];
  }
  __syncthreads();
  if (tid == 0) {
    const float sc = scoreB[b];
    float se = 0.f;
    for (int j = 0; j < TOPK; ++j) se += expf(sqrtf(fmaxf(dist2[j], 0.f)));
    outp[b] = (1.f - expf(sc)/se) * sc;
  }
}

// ---------------- anomaly map: 28->224 bilinear then 33-tap separable gaussian ----------------
__global__ void resize_kernel(const float* __restrict__ pscore, float* __restrict__ amap) {
  const int idx = blockIdx.x*256 + threadIdx.x;
  if (idx >= B_SZ*IMGSZ*IMGSZ) return;
  const int b = idx / (IMGSZ*IMGSZ);
  const int r = idx % (IMGSZ*IMGSZ);
  const int oy = r / IMGSZ, ox = r % IMGSZ;
  const float sy = oy*0.125f - 0.4375f, sx = ox*0.125f - 0.4375f;
  const int y0 = (int)floorf(sy), x0 = (int)floorf(sx);
  const float fy = sy - y0, fx = sx - x0;
  const int y0c = min(max(y0, 0), H2-1), y1c = min(max(y0+1, 0), H2-1);
  const int x0c = min(max(x0, 0), W2-1), x1c = min(max(x0+1, 0), W2-1);
  const float* p = pscore + b*(H2*W2);
  amap[idx] = (1.f-fy)*((1.f-fx)*p[y0c*W2+x0c] + fx*p[y0c*W2+x1c]) +
                   fy *((1.f-fx)*p[y1c*W2+x0c] + fx*p[y1c*W2+x1c]);
}

__device__ __forceinline__ void make_gauss(float* kr, float* kinv, int tid) {
  if (tid < 33) { const float x = (tid - 16) * 0.25f; kr[tid] = expf(-0.5f*x*x); }
  __syncthreads();
  if (tid == 0) { float s = 0.f; for (int i = 0; i < 33; ++i) s += kr[i]; *kinv = 1.0f/s; }
  __syncthreads();
}

__global__ __launch_bounds__(256) void blurh_kernel(const float* __restrict__ amap,
                                                    float* __restrict__ tmp) {
  __shared__ float kr[33]; __shared__ float kinv; __shared__ float row[256];
  const int tid = threadIdx.x;
  make_gauss(kr, &kinv, tid);
  const int b = blockIdx.x / IMGSZ, y = blockIdx.x % IMGSZ;
  const float* src = amap + (size_t)(b*IMGSZ + y)*IMGSZ;
  const int xx = tid - 16;
  row[tid] = (xx >= 0 && xx < IMGSZ) ? src[xx] : 0.f;
  __syncthreads();
  if (tid < IMGSZ) {
    float s = 0.f;
    #pragma unroll
    for (int j = 0; j < 33; ++j) s = fmaf(kr[j], row[tid + j], s);
    tmp[(size_t)(b*IMGSZ + y)*IMGSZ + tid] = s * kinv;
  }
}

__global__ __launch_bounds__(256) void blurv_kernel(const float* __restrict__ tmp,
                                                    float* __restrict__ outp) {
  __shared__ float kr[33]; __shared__ float kinv;
  const int tid = threadIdx.x;
  make_gauss(kr, &kinv, tid);
  const int b = blockIdx.x / IMGSZ, y = blockIdx.x % IMGSZ;
  if (tid < IMGSZ) {
    float s = 0.f;
    #pragma unroll
    for (int j = 0; j < 33; ++j) {
      const int yy = y + j - 16;
      if (yy >= 0 && yy < IMGSZ) s = fmaf(kr[j], tmp[(size_t)(b*IMGSZ + yy)*IMGSZ + tid], s);
    }
    outp[(size_t)(b*IMGSZ + y)*IMGSZ + tid] = s * kinv;
  }
}

// ---------------- launch ----------------
extern "C" void kernel_launch(void* const* d_in, const int* in_sizes, int n_in,
                              void* d_out, int out_size, void* d_ws, size_t ws_size,
                              hipStream_t stream) {
  (void)in_sizes; (void)n_in; (void)out_size; (void)ws_size;
  const float* feat2 = (const float*)d_in[0];
  const float* feat3 = (const float*)d_in[1];
  const float* bank  = (const float*)d_in[2];
  float* out = (float*)d_out;

  char* w = (char*)d_ws;
  size_t off = 0;
  auto take = [&](size_t bytes) -> void* {
    void* p = w + off;
    off = (off + bytes + 255) & ~(size_t)255;
    return p;
  };
  float*  embT    = (float*) take(sizeof(float)*(size_t)CDIM*N_EMB);     // 9.6 MB
  ushort* ehi     = (ushort*)take(sizeof(ushort)*(size_t)N_EMB*CDIM);    // 4.8 MB
  ushort* elo     = (ushort*)take(sizeof(ushort)*(size_t)N_EMB*CDIM);
  ushort* bhi     = (ushort*)take(sizeof(ushort)*(size_t)MP2*CDIM);      // 23.2 MB
  ushort* blo     = (ushort*)take(sizeof(ushort)*(size_t)MP2*CDIM);
  float*  xn      = (float*) take(sizeof(float)*N_EMB);
  float*  yn      = (float*) take(sizeof(float)*MP2);
  float*  pmin    = (float*) take(sizeof(float)*(size_t)GY*N_EMB);
  int*    parg    = (int*)   take(sizeof(int)*(size_t)GY*N_EMB);
  float*  pscore  = (float*) take(sizeof(float)*N_EMB);
  int*    ploc    = (int*)   take(sizeof(int)*N_EMB);
  float*  scoreB  = (float*) take(sizeof(float)*B_SZ);
  int*    nnidx   = (int*)   take(sizeof(int)*B_SZ);
  float*  mfnorm  = (float*) take(sizeof(float)*B_SZ);
  float*  maxfeat = (float*) take(sizeof(float)*B_SZ*CDIM);
  float*  candv   = (float*) take(sizeof(float)*B_SZ*SPLIT*TOPK);
  int*    candi   = (int*)   take(sizeof(int)*B_SZ*SPLIT*TOPK);
  float*  amap    = (float*) take(sizeof(float)*(size_t)B_SZ*IMGSZ*IMGSZ);
  float*  tmpb    = (float*) take(sizeof(float)*(size_t)B_SZ*IMGSZ*IMGSZ);

  // embedding f32 [C][N] + bf16-split operands
  hipLaunchKernelGGL(pool2_kernel,   dim3(B_SZ*C2), dim3(256), 0, stream, feat2, embT);
  hipLaunchKernelGGL(pool3up_kernel, dim3(B_SZ*C3), dim3(256), 0, stream, feat3, embT);
  hipLaunchKernelGGL(embconv, dim3(N_EMB/32, CDIM/32), dim3(256), 0, stream, embT, ehi, elo);
  hipLaunchKernelGGL(conv_bank, dim3((unsigned)((size_t)MP2*CDIM/4/256)), dim3(256), 0, stream,
                     bank, bhi, blo);
  hipLaunchKernelGGL(xn_kernel, dim3((N_EMB+255)/256), dim3(256), 0, stream, embT, xn);
  hipLaunchKernelGGL(yn_kernel, dim3(MP2/4), dim3(256), 0, stream, bank, yn);

  // fused distance GEMM (MFMA) with min/argmin, XCD-pinned slices
  hipLaunchKernelGGL(distmin_mfma, dim3(98, GY), dim3(512), 0, stream,
                     ehi, elo, bhi, blo, xn, yn, pmin, parg);
  hipLaunchKernelGGL(reduce_chunks, dim3((N_EMB+255)/256), dim3(256), 0, stream,
                     pmin, parg, pscore, ploc);

  // pred_score path (exact f32)
  hipLaunchKernelGGL(perb_argmax, dim3(B_SZ), dim3(256), 0, stream,
                     pscore, ploc, embT, xn, scoreB, nnidx, maxfeat, mfnorm);
  hipLaunchKernelGGL(topk_partial, dim3(SPLIT), dim3(512), 0, stream,
                     bank, yn, nnidx, candv, candi);
  hipLaunchKernelGGL(final_score, dim3(B_SZ), dim3(320), 0, stream,
                     bank, yn, candv, candi, maxfeat, mfnorm, scoreB, out);

  // anomaly map path
  hipLaunchKernelGGL(resize_kernel, dim3((B_SZ*IMGSZ*IMGSZ+255)/256), dim3(256), 0, stream,
                     pscore, amap);
  hipLaunchKernelGGL(blurh_kernel, dim3(B_SZ*IMGSZ), dim3(256), 0, stream, amap, tmpb);
  hipLaunchKernelGGL(blurv_kernel, dim3(B_SZ*IMGSZ), dim3(256), 0, stream, tmpb, out + B_SZ);
}

// Round 6
// 1728.338 us; speedup vs baseline: 1.0332x; 1.0332x over previous
//
#include <hip/hip_runtime.h>
#include <cfloat>
#include <climits>

// ---------------- problem constants ----------------
#define B_SZ   8
#define C2     128
#define C3     256
#define H2     28
#define W2     28
#define H3     14
#define W3     14
#define CDIM   384
#define N_EMB  (B_SZ*H2*W2)      // 6272
#define NPAD   6400              // emb rows padded for safe streaming (tail n-tile)
#define M_BANK 30000
#define MP2    30208             // padded to multiple of 64
#define NBLK   (MP2/64)          // 472 blocks, one 64-row bank tile each
#define NTILE  256               // n processed per block iteration
#define NTILES 25                // ceil(6272/256)
#define IMGSZ  224
#define TOPK   9
#define SPLIT  32                // per-b segments for top-k
#define LDSROW 392               // 384 + 8 bf16 pad (784B rows -> balanced LDS quads)

typedef __attribute__((ext_vector_type(8))) short short8v;   // bf16x8 bits (4 VGPR)
typedef __attribute__((ext_vector_type(4))) float f32x4;

// ---------------- bf16 split helpers ----------------
__device__ __forceinline__ ushort f2bf(float x) {
  union { float f; unsigned u; } a; a.f = x;
  const unsigned r = a.u + 0x7fffu + ((a.u >> 16) & 1u);   // RNE
  return (ushort)(r >> 16);
}
__device__ __forceinline__ float bf2f(ushort b) {
  union { float f; unsigned u; } a; a.u = ((unsigned)b) << 16;
  return a.f;
}

// ---------------- embedding build ----------------
__global__ __launch_bounds__(256) void pool2_kernel(const float* __restrict__ feat2,
                                                    float* __restrict__ embT) {
  const int bc = blockIdx.x;            // b*128+c
  const int b = bc >> 7, c = bc & 127;
  __shared__ float plane[H2*W2];
  const float* src = feat2 + (size_t)bc * (H2*W2);
  for (int i = threadIdx.x; i < H2*W2; i += 256) plane[i] = src[i];
  __syncthreads();
  for (int i = threadIdx.x; i < H2*W2; i += 256) {
    const int h = i / W2, w = i % W2;
    float s = 0.f;
    #pragma unroll
    for (int dh = -1; dh <= 1; ++dh)
      #pragma unroll
      for (int dw = -1; dw <= 1; ++dw) {
        const int hh = h + dh, ww = w + dw;
        if (hh >= 0 && hh < H2 && ww >= 0 && ww < W2) s += plane[hh*W2 + ww];
      }
    embT[(size_t)c * N_EMB + (size_t)b * (H2*W2) + i] = s * (1.0f/9.0f);
  }
}

__global__ __launch_bounds__(256) void pool3up_kernel(const float* __restrict__ feat3,
                                                      float* __restrict__ embT) {
  const int bc = blockIdx.x;            // b*256+c
  const int b = bc >> 8, c = bc & 255;
  __shared__ float plane[H3*W3];
  __shared__ float pooled[H3*W3];
  const float* src = feat3 + (size_t)bc * (H3*W3);
  for (int i = threadIdx.x; i < H3*W3; i += 256) plane[i] = src[i];
  __syncthreads();
  for (int i = threadIdx.x; i < H3*W3; i += 256) {
    const int h = i / W3, w = i % W3;
    float s = 0.f;
    #pragma unroll
    for (int dh = -1; dh <= 1; ++dh)
      #pragma unroll
      for (int dw = -1; dw <= 1; ++dw) {
        const int hh = h + dh, ww = w + dw;
        if (hh >= 0 && hh < H3 && ww >= 0 && ww < W3) s += plane[hh*W3 + ww];
      }
    pooled[i] = s * (1.0f/9.0f);
  }
  __syncthreads();
  for (int i = threadIdx.x; i < H2*W2; i += 256) {
    const int h = i / W2, w = i % W2;
    const float sy = h*0.5f - 0.25f, sx = w*0.5f - 0.25f;
    const int y0 = (int)floorf(sy), x0 = (int)floorf(sx);
    const float fy = sy - y0, fx = sx - x0;
    const int y0c = min(max(y0, 0), H3-1),   y1c = min(max(y0+1, 0), H3-1);
    const int x0c = min(max(x0, 0), W3-1),   x1c = min(max(x0+1, 0), W3-1);
    const float v =
        (1.f-fy)*((1.f-fx)*pooled[y0c*W3+x0c] + fx*pooled[y0c*W3+x1c]) +
             fy *((1.f-fx)*pooled[y1c*W3+x0c] + fx*pooled[y1c*W3+x1c]);
    embT[(size_t)(C2 + c) * N_EMB + (size_t)b * (H2*W2) + i] = v;
  }
}

// transpose+convert: embT[C][N] f32 -> ehi/elo [N][C] bf16
__global__ __launch_bounds__(256) void embconv(const float* __restrict__ embT,
                                               ushort* __restrict__ eh,
                                               ushort* __restrict__ el) {
  __shared__ float tile[32][33];
  const int tid = threadIdx.x;
  const int n0 = blockIdx.x*32, c0 = blockIdx.y*32;
  #pragma unroll
  for (int p = 0; p < 4; ++p) {
    const int c = p*8 + (tid >> 5);
    const int n = tid & 31;
    tile[n][c] = embT[(size_t)(c0 + c)*N_EMB + n0 + n];
  }
  __syncthreads();
  const int nr = tid >> 3, cq = (tid & 7) << 2;
  ushort4 h, l;
  float v0 = tile[nr][cq+0], v1 = tile[nr][cq+1], v2 = tile[nr][cq+2], v3 = tile[nr][cq+3];
  h.x = f2bf(v0); h.y = f2bf(v1); h.z = f2bf(v2); h.w = f2bf(v3);
  l.x = f2bf(v0 - bf2f(h.x)); l.y = f2bf(v1 - bf2f(h.y));
  l.z = f2bf(v2 - bf2f(h.z)); l.w = f2bf(v3 - bf2f(h.w));
  *(ushort4*)&eh[(size_t)(n0+nr)*CDIM + c0 + cq] = h;
  *(ushort4*)&el[(size_t)(n0+nr)*CDIM + c0 + cq] = l;
}

// bank f32 [30000][384] -> bh/bl bf16 [MP2][384] (pad rows zero)
__global__ __launch_bounds__(256) void conv_bank(const float* __restrict__ bank,
                                                 ushort* __restrict__ bh,
                                                 ushort* __restrict__ bl) {
  const size_t i = (size_t)blockIdx.x*256 + threadIdx.x;   // one float4 per thread
  if (i >= (size_t)MP2*CDIM/4) return;
  const size_t e = i*4;
  const int row = (int)(e / CDIM);
  ushort4 h = {0,0,0,0}, l = {0,0,0,0};
  if (row < M_BANK) {
    const float4 v = *(const float4*)&bank[e];
    h.x = f2bf(v.x); h.y = f2bf(v.y); h.z = f2bf(v.z); h.w = f2bf(v.w);
    l.x = f2bf(v.x - bf2f(h.x)); l.y = f2bf(v.y - bf2f(h.y));
    l.z = f2bf(v.z - bf2f(h.z)); l.w = f2bf(v.w - bf2f(h.w));
  }
  *(ushort4*)&bh[e] = h;
  *(ushort4*)&bl[e] = l;
}

// ---------------- norms ----------------
__global__ void xn_kernel(const float* __restrict__ embT, float* __restrict__ xn) {
  const int n = blockIdx.x*256 + threadIdx.x;
  if (n >= N_EMB) return;
  float s = 0.f;
  for (int c = 0; c < CDIM; ++c) {
    const float v = embT[(size_t)c * N_EMB + n];
    s = fmaf(v, v, s);
  }
  xn[n] = s;
}

__global__ void yn_kernel(const float* __restrict__ bank, float* __restrict__ yn) {
  const int wave = threadIdx.x >> 6, lane = threadIdx.x & 63;
  const int m = blockIdx.x*4 + wave;
  if (m >= MP2) return;
  if (m >= M_BANK) { if (lane == 0) yn[m] = 1e30f; return; }
  const float* row = bank + (size_t)m * CDIM;
  float s = 0.f;
  #pragma unroll
  for (int j = 0; j < CDIM/64; ++j) {
    const float v = row[lane + j*64];
    s = fmaf(v, v, s);
  }
  #pragma unroll
  for (int sh = 32; sh > 0; sh >>= 1) s += __shfl_down(s, sh);
  if (lane == 0) yn[m] = s;
}

// ---------------- fused distance GEMM (bf16-split MFMA) + min/argmin ----------------
// FLIPPED: each block stages a PRIVATE 64-row bank tile in LDS (bank read from
// HBM exactly once), then streams ALL emb n-tiles (L2-resident by construction:
// every block sweeps n in the same order). Partial min over the block's 64 rows
// is written per n; a 472-way lex reduce follows.
__global__ __launch_bounds__(512, 2) void distmin_mfma(
    const ushort* __restrict__ ehi, const ushort* __restrict__ elo,
    const ushort* __restrict__ bhi, const ushort* __restrict__ blo,
    const float* __restrict__ yn,
    float* __restrict__ pmin, int* __restrict__ parg)
{
  __shared__ ushort bsh[64*LDSROW];
  __shared__ ushort bsl[64*LDSROW];
  __shared__ float rv[2][NTILE];
  __shared__ int   ri[2][NTILE];

  const int tid = threadIdx.x;
  const int wave = tid >> 6, lane = tid & 63;
  const int lg = lane >> 4, lr = lane & 15;
  const int mh = wave & 1;          // m-half (32 rows)
  const int nq = wave >> 1;         // n-quarter (64 cols of the 256 n-tile)
  const int mbase = blockIdx.x * 64;

  // stage bank tile (hi+lo), full K, row-padded — once per kernel
  for (int idx = tid; idx < 64*48; idx += 512) {
    const int r = idx / 48, c8 = (idx % 48) * 8;
    *(short8v*)&bsh[r*LDSROW + c8] = *(const short8v*)&bhi[(size_t)(mbase + r)*CDIM + c8];
    *(short8v*)&bsl[r*LDSROW + c8] = *(const short8v*)&blo[(size_t)(mbase + r)*CDIM + c8];
  }
  __syncthreads();

  // per-lane yn for this lane's 8 m-rows (2 frags x 4 rows)
  const float4 y40 = *(const float4*)&yn[mbase + mh*32 + lg*4];
  const float4 y41 = *(const float4*)&yn[mbase + mh*32 + 16 + lg*4];
  const float yv0[4] = {y40.x, y40.y, y40.z, y40.w};
  const float yv1[4] = {y41.x, y41.y, y41.z, y41.w};

  const int abase = (mh*32 + lr)*LDSROW + lg*8;   // A-frag LDS base (f adds 16*LDSROW)

  for (int nt = 0; nt < NTILES; ++nt) {
    const int nw = nt*NTILE + nq*64;              // wave's n-base
    const ushort* ebh = ehi + (size_t)(nw + lr)*CDIM + lg*8;
    const ushort* ebl = elo + (size_t)(nw + lr)*CDIM + lg*8;

    f32x4 acc[2][4];
    #pragma unroll
    for (int f = 0; f < 2; ++f)
      #pragma unroll
      for (int t = 0; t < 4; ++t) acc[f][t] = (f32x4){0.f, 0.f, 0.f, 0.f};

    #pragma unroll
    for (int kc = 0; kc < 12; ++kc) {
      const int k0 = kc*32;
      const short8v a0h = *(const short8v*)&bsh[abase + k0];
      const short8v a0l = *(const short8v*)&bsl[abase + k0];
      const short8v a1h = *(const short8v*)&bsh[abase + 16*LDSROW + k0];
      const short8v a1l = *(const short8v*)&bsl[abase + 16*LDSROW + k0];
      #pragma unroll
      for (int t = 0; t < 4; ++t) {
        const short8v vbh = *(const short8v*)&ebh[(size_t)t*16*CDIM + k0];
        const short8v vbl = *(const short8v*)&ebl[(size_t)t*16*CDIM + k0];
        acc[0][t] = __builtin_amdgcn_mfma_f32_16x16x32_bf16(a0h, vbh, acc[0][t], 0, 0, 0);
        acc[0][t] = __builtin_amdgcn_mfma_f32_16x16x32_bf16(a0h, vbl, acc[0][t], 0, 0, 0);
        acc[0][t] = __builtin_amdgcn_mfma_f32_16x16x32_bf16(a0l, vbh, acc[0][t], 0, 0, 0);
        acc[1][t] = __builtin_amdgcn_mfma_f32_16x16x32_bf16(a1h, vbh, acc[1][t], 0, 0, 0);
        acc[1][t] = __builtin_amdgcn_mfma_f32_16x16x32_bf16(a1h, vbl, acc[1][t], 0, 0, 0);
        acc[1][t] = __builtin_amdgcn_mfma_f32_16x16x32_bf16(a1l, vbh, acc[1][t], 0, 0, 0);
      }
    }

    // epilogue: per n (t,lr), min over this wave's 8 m-rows (ascending m -> first)
    #pragma unroll
    for (int t = 0; t < 4; ++t) {
      float bv = FLT_MAX; int bi = INT_MAX;
      #pragma unroll
      for (int f = 0; f < 2; ++f)
        #pragma unroll
        for (int r = 0; r < 4; ++r) {
          const float d = (f ? yv1[r] : yv0[r]) - 2.0f*acc[f][t][r];
          const int m = mbase + mh*32 + f*16 + lg*4 + r;
          if (d < bv) { bv = d; bi = m; }
        }
      // reduce over lg (lanes xor 16, 32 hold same n), lex first-index
      #pragma unroll
      for (int off = 16; off < 64; off <<= 1) {
        const float ov = __shfl_xor(bv, off);
        const int   oi = __shfl_xor(bi, off);
        if (ov < bv || (ov == bv && oi < bi)) { bv = ov; bi = oi; }
      }
      if (lg == 0) { rv[mh][nq*64 + t*16 + lr] = bv; ri[mh][nq*64 + t*16 + lr] = bi; }
    }
    __syncthreads();
    if (tid < NTILE) {
      const int n = nt*NTILE + tid;
      if (n < N_EMB) {
        float v0 = rv[0][tid]; int i0 = ri[0][tid];
        const float v1 = rv[1][tid]; const int i1 = ri[1][tid];
        if (v1 < v0 || (v1 == v0 && i1 < i0)) { v0 = v1; i0 = i1; }
        pmin[(size_t)blockIdx.x*N_EMB + n] = v0;
        parg[(size_t)blockIdx.x*N_EMB + n] = i0;
      }
    }
    __syncthreads();
  }
}

// combine NBLK partials -> patch score (sqrt(xn + min)) + location
__global__ void reduce_chunks(const float* __restrict__ pmin, const int* __restrict__ parg,
                              const float* __restrict__ xn,
                              float* __restrict__ pscore, int* __restrict__ ploc) {
  const int n = blockIdx.x*256 + threadIdx.x;
  if (n >= N_EMB) return;
  float bv = pmin[n]; int bi = parg[n];
  for (int y = 1; y < NBLK; ++y) {
    const float v = pmin[(size_t)y*N_EMB + n];
    const int ix = parg[(size_t)y*N_EMB + n];
    if (v < bv || (v == bv && ix < bi)) { bv = v; bi = ix; }
  }
  pscore[n] = sqrtf(fmaxf(xn[n] + bv, 0.f));
  ploc[n] = bi;
}

// ---------------- per-batch argmax + gathers ----------------
__global__ __launch_bounds__(256) void perb_argmax(
    const float* __restrict__ pscore, const int* __restrict__ ploc,
    const float* __restrict__ embT,   const float* __restrict__ xn,
    float* __restrict__ scoreB, int* __restrict__ nnidx,
    float* __restrict__ maxfeat, float* __restrict__ mfnorm)
{
  const int b = blockIdx.x, tid = threadIdx.x;
  __shared__ float sv[256]; __shared__ int si[256];
  float bv = -FLT_MAX; int bi = INT_MAX;
  for (int p = tid; p < H2*W2; p += 256) {
    const float v = pscore[b*(H2*W2) + p];
    if (v > bv) { bv = v; bi = p; }
  }
  sv[tid] = bv; si[tid] = bi;
  __syncthreads();
  for (int s = 128; s > 0; s >>= 1) {
    if (tid < s) {
      if (sv[tid+s] > sv[tid] || (sv[tid+s] == sv[tid] && si[tid+s] < si[tid])) {
        sv[tid] = sv[tid+s]; si[tid] = si[tid+s];
      }
    }
    __syncthreads();
  }
  const int n = b*(H2*W2) + si[0];
  if (tid == 0) { scoreB[b] = sv[0]; nnidx[b] = ploc[n]; mfnorm[b] = xn[n]; }
  for (int c = tid; c < CDIM; c += 256) maxfeat[b*CDIM + c] = embT[(size_t)c*N_EMB + n];
}

// ---------------- per-batch 9-NN of nn_sample: 8 batches fused per segment ----------------
__global__ __launch_bounds__(512) void topk_partial(
    const float* __restrict__ bank, const float* __restrict__ yn,
    const int* __restrict__ nnidx, float* __restrict__ candv, int* __restrict__ candi)
{
  const int seg = blockIdx.x, tid = threadIdx.x;
  __shared__ float nnf[B_SZ*CDIM];        // 12 KB
  __shared__ float d2s[B_SZ][1024];       // 32 KB
  __shared__ float nrm[B_SZ];
  for (int i = tid; i < B_SZ*CDIM; i += 512) {
    const int b = i / CDIM, c = i % CDIM;
    nnf[i] = bank[(size_t)nnidx[b]*CDIM + c];
  }
  if (tid < B_SZ) nrm[tid] = yn[nnidx[tid]];
  __syncthreads();
  const int per = (M_BANK + SPLIT - 1) / SPLIT;   // 938
  const int mlo = seg * per;
  const int mhi = min(mlo + per, M_BANK);
  #pragma unroll
  for (int i = 0; i < 2; ++i) {
    const int p = i*512 + tid;
    const int m = mlo + p;
    if (m < mhi) {
      const float* row = bank + (size_t)m*CDIM;
      float dot[B_SZ];
      #pragma unroll
      for (int b = 0; b < B_SZ; ++b) dot[b] = 0.f;
      for (int c = 0; c < CDIM; c += 4) {
        const float4 r4 = *(const float4*)&row[c];
        #pragma unroll
        for (int b = 0; b < B_SZ; ++b) {
          dot[b] = fmaf(r4.x, nnf[b*CDIM+c+0], dot[b]);
          dot[b] = fmaf(r4.y, nnf[b*CDIM+c+1], dot[b]);
          dot[b] = fmaf(r4.z, nnf[b*CDIM+c+2], dot[b]);
          dot[b] = fmaf(r4.w, nnf[b*CDIM+c+3], dot[b]);
        }
      }
      const float ym = yn[m];
      #pragma unroll
      for (int b = 0; b < B_SZ; ++b) d2s[b][p] = nrm[b] - 2.f*dot[b] + ym;
    } else {
      #pragma unroll
      for (int b = 0; b < B_SZ; ++b) d2s[b][p] = FLT_MAX;
    }
  }
  __syncthreads();
  const int b = tid >> 6, lane = tid & 63;
  for (int r = 0; r < TOPK; ++r) {
    float bv = FLT_MAX; int bp = INT_MAX;
    #pragma unroll
    for (int s = 0; s < 16; ++s) {
      const int p = lane + s*64;
      const float v = d2s[b][p];
      if (v < bv || (v == bv && p < bp)) { bv = v; bp = p; }
    }
    #pragma unroll
    for (int off = 32; off > 0; off >>= 1) {
      const float ov = __shfl_down(bv, off);
      const int   op = __shfl_down(bp, off);
      if (ov < bv || (ov == bv && op < bp)) { bv = ov; bp = op; }
    }
    if (lane == 0) {
      candv[((size_t)b*SPLIT + seg)*TOPK + r] = bv;
      candi[((size_t)b*SPLIT + seg)*TOPK + r] = mlo + bp;
      d2s[b][bp] = FLT_MAX;
    }
    __syncthreads();
  }
}

// ---------------- merge candidates, compute pred_score ----------------
__global__ __launch_bounds__(320) void final_score(
    const float* __restrict__ bank, const float* __restrict__ yn,
    const float* __restrict__ candv, const int* __restrict__ candi,
    const float* __restrict__ maxfeat, const float* __restrict__ mfnorm,
    const float* __restrict__ scoreB, float* __restrict__ outp)
{
  const int b = blockIdx.x, tid = threadIdx.x;
  __shared__ float av[SPLIT*TOPK]; __shared__ int ai[SPLIT*TOPK];
  __shared__ int sup[TOPK];
  __shared__ float dist2[TOPK];
  if (tid < SPLIT*TOPK) {
    av[tid] = candv[(size_t)b*SPLIT*TOPK + tid];
    ai[tid] = candi[(size_t)b*SPLIT*TOPK + tid];
  }
  __syncthreads();
  if (tid == 0) {
    for (int r = 0; r < TOPK; ++r) {
      float bv = FLT_MAX; int bi = INT_MAX; int bp = -1;
      for (int p = 0; p < SPLIT*TOPK; ++p) {
        if (av[p] < bv || (av[p] == bv && ai[p] < bi)) { bv = av[p]; bi = ai[p]; bp = p; }
      }
      sup[r] = bi; av[bp] = FLT_MAX;
    }
  }
  __syncthreads();
  if (tid < TOPK*32) {
    const int j = tid >> 5, l = tid & 31;
    const float* row = bank + (size_t)sup[j]*CDIM;
    const float* mf  = maxfeat + b*CDIM;
    float p = 0.f;
    for (int c = l; c < CDIM; c += 32) p = fmaf(row[c], mf[c], p);
    #pragma unroll
    for (int s = 16; s > 0; s >>= 1) p += __shfl_down(p, s, 32);
    if (l == 0) dist2[j] = mfnorm[b] - 2.f*p + yn[sup[j]];
  }
  __syncthreads();
  if (tid == 0) {
    const float sc = scoreB[b];
    float se = 0.f;
    for (int j = 0; j < TOPK; ++j) se += expf(sqrtf(fmaxf(dist2[j], 0.f)));
    outp[b] = (1.f - expf(sc)/se) * sc;
  }
}

// ---------------- anomaly map: 28->224 bilinear then 33-tap separable gaussian ----------------
__global__ void resize_kernel(const float* __restrict__ pscore, float* __restrict__ amap) {
  const int idx = blockIdx.x*256 + threadIdx.x;
  if (idx >= B_SZ*IMGSZ*IMGSZ) return;
  const int b = idx / (IMGSZ*IMGSZ);
  const int r = idx % (IMGSZ*IMGSZ);
  const int oy = r / IMGSZ, ox = r % IMGSZ;
  const float sy = oy*0.125f - 0.4375f, sx = ox*0.125f - 0.4375f;
  const int y0 = (int)floorf(sy), x0 = (int)floorf(sx);
  const float fy = sy - y0, fx = sx - x0;
  const int y0c = min(max(y0, 0), H2-1), y1c = min(max(y0+1, 0), H2-1);
  const int x0c = min(max(x0, 0), W2-1), x1c = min(max(x0+1, 0), W2-1);
  const float* p = pscore + b*(H2*W2);
  amap[idx] = (1.f-fy)*((1.f-fx)*p[y0c*W2+x0c] + fx*p[y0c*W2+x1c]) +
                   fy *((1.f-fx)*p[y1c*W2+x0c] + fx*p[y1c*W2+x1c]);
}

__device__ __forceinline__ void make_gauss(float* kr, float* kinv, int tid) {
  if (tid < 33) { const float x = (tid - 16) * 0.25f; kr[tid] = expf(-0.5f*x*x); }
  __syncthreads();
  if (tid == 0) { float s = 0.f; for (int i = 0; i < 33; ++i) s += kr[i]; *kinv = 1.0f/s; }
  __syncthreads();
}

__global__ __launch_bounds__(256) void blurh_kernel(const float* __restrict__ amap,
                                                    float* __restrict__ tmp) {
  __shared__ float kr[33]; __shared__ float kinv; __shared__ float row[256];
  const int tid = threadIdx.x;
  make_gauss(kr, &kinv, tid);
  const int b = blockIdx.x / IMGSZ, y = blockIdx.x % IMGSZ;
  const float* src = amap + (size_t)(b*IMGSZ + y)*IMGSZ;
  const int xx = tid - 16;
  row[tid] = (xx >= 0 && xx < IMGSZ) ? src[xx] : 0.f;
  __syncthreads();
  if (tid < IMGSZ) {
    float s = 0.f;
    #pragma unroll
    for (int j = 0; j < 33; ++j) s = fmaf(kr[j], row[tid + j], s);
    tmp[(size_t)(b*IMGSZ + y)*IMGSZ + tid] = s * kinv;
  }
}

__global__ __launch_bounds__(256) void blurv_kernel(const float* __restrict__ tmp,
                                                    float* __restrict__ outp) {
  __shared__ float kr[33]; __shared__ float kinv;
  const int tid = threadIdx.x;
  make_gauss(kr, &kinv, tid);
  const int b = blockIdx.x / IMGSZ, y = blockIdx.x % IMGSZ;
  if (tid < IMGSZ) {
    float s = 0.f;
    #pragma unroll
    for (int j = 0; j < 33; ++j) {
      const int yy = y + j - 16;
      if (yy >= 0 && yy < IMGSZ) s = fmaf(kr[j], tmp[(size_t)(b*IMGSZ + yy)*IMGSZ + tid], s);
    }
    outp[(size_t)(b*IMGSZ + y)*IMGSZ + tid] = s * kinv;
  }
}

// ---------------- launch ----------------
extern "C" void kernel_launch(void* const* d_in, const int* in_sizes, int n_in,
                              void* d_out, int out_size, void* d_ws, size_t ws_size,
                              hipStream_t stream) {
  (void)in_sizes; (void)n_in; (void)out_size; (void)ws_size;
  const float* feat2 = (const float*)d_in[0];
  const float* feat3 = (const float*)d_in[1];
  const float* bank  = (const float*)d_in[2];
  float* out = (float*)d_out;

  char* w = (char*)d_ws;
  size_t off = 0;
  auto take = [&](size_t bytes) -> void* {
    void* p = w + off;
    off = (off + bytes + 255) & ~(size_t)255;
    return p;
  };
  float*  embT    = (float*) take(sizeof(float)*(size_t)CDIM*N_EMB);     // 9.6 MB
  ushort* ehi     = (ushort*)take(sizeof(ushort)*(size_t)NPAD*CDIM);     // 4.9 MB
  ushort* elo     = (ushort*)take(sizeof(ushort)*(size_t)NPAD*CDIM);
  ushort* bhi     = (ushort*)take(sizeof(ushort)*(size_t)MP2*CDIM);      // 23.2 MB
  ushort* blo     = (ushort*)take(sizeof(ushort)*(size_t)MP2*CDIM);
  float*  xn      = (float*) take(sizeof(float)*N_EMB);
  float*  yn      = (float*) take(sizeof(float)*MP2);
  float*  pmin    = (float*) take(sizeof(float)*(size_t)NBLK*N_EMB);     // 11.8 MB
  int*    parg    = (int*)   take(sizeof(int)*(size_t)NBLK*N_EMB);       // 11.8 MB
  float*  pscore  = (float*) take(sizeof(float)*N_EMB);
  int*    ploc    = (int*)   take(sizeof(int)*N_EMB);
  float*  scoreB  = (float*) take(sizeof(float)*B_SZ);
  int*    nnidx   = (int*)   take(sizeof(int)*B_SZ);
  float*  mfnorm  = (float*) take(sizeof(float)*B_SZ);
  float*  maxfeat = (float*) take(sizeof(float)*B_SZ*CDIM);
  float*  candv   = (float*) take(sizeof(float)*B_SZ*SPLIT*TOPK);
  int*    candi   = (int*)   take(sizeof(int)*B_SZ*SPLIT*TOPK);
  float*  amap    = (float*) take(sizeof(float)*(size_t)B_SZ*IMGSZ*IMGSZ);
  float*  tmpb    = (float*) take(sizeof(float)*(size_t)B_SZ*IMGSZ*IMGSZ);

  // embedding f32 [C][N] + bf16-split operands
  hipLaunchKernelGGL(pool2_kernel,   dim3(B_SZ*C2), dim3(256), 0, stream, feat2, embT);
  hipLaunchKernelGGL(pool3up_kernel, dim3(B_SZ*C3), dim3(256), 0, stream, feat3, embT);
  hipLaunchKernelGGL(embconv, dim3(N_EMB/32, CDIM/32), dim3(256), 0, stream, embT, ehi, elo);
  hipLaunchKernelGGL(conv_bank, dim3((unsigned)((size_t)MP2*CDIM/4/256)), dim3(256), 0, stream,
                     bank, bhi, blo);
  hipLaunchKernelGGL(xn_kernel, dim3((N_EMB+255)/256), dim3(256), 0, stream, embT, xn);
  hipLaunchKernelGGL(yn_kernel, dim3(MP2/4), dim3(256), 0, stream, bank, yn);

  // fused distance GEMM (MFMA): bank tile in LDS, emb streamed (L2-resident)
  hipLaunchKernelGGL(distmin_mfma, dim3(NBLK), dim3(512), 0, stream,
                     ehi, elo, bhi, blo, yn, pmin, parg);
  hipLaunchKernelGGL(reduce_chunks, dim3((N_EMB+255)/256), dim3(256), 0, stream,
                     pmin, parg, xn, pscore, ploc);

  // pred_score path (exact f32)
  hipLaunchKernelGGL(perb_argmax, dim3(B_SZ), dim3(256), 0, stream,
                     pscore, ploc, embT, xn, scoreB, nnidx, maxfeat, mfnorm);
  hipLaunchKernelGGL(topk_partial, dim3(SPLIT), dim3(512), 0, stream,
                     bank, yn, nnidx, candv, candi);
  hipLaunchKernelGGL(final_score, dim3(B_SZ), dim3(320), 0, stream,
                     bank, yn, candv, candi, maxfeat, mfnorm, scoreB, out);

  // anomaly map path
  hipLaunchKernelGGL(resize_kernel, dim3((B_SZ*IMGSZ*IMGSZ+255)/256), dim3(256), 0, stream,
                     pscore, amap);
  hipLaunchKernelGGL(blurh_kernel, dim3(B_SZ*IMGSZ), dim3(256), 0, stream, amap, tmpb);
  hipLaunchKernelGGL(blurv_kernel, dim3(B_SZ*IMGSZ), dim3(256), 0, stream, tmpb, out + B_SZ);
}

// Round 7
// 804.133 us; speedup vs baseline: 2.2206x; 2.1493x over previous
//
#include <hip/hip_runtime.h>
#include <cfloat>
#include <climits>

// ---------------- problem constants ----------------
#define B_SZ   8
#define C2     128
#define C3     256
#define H2     28
#define W2     28
#define H3     14
#define W3     14
#define CDIM   384
#define N_EMB  (B_SZ*H2*W2)      // 6272
#define NPAD   6656              // 13 * 512 (block n-sweep granularity)
#define NFRAG  (NPAD/16)         // 416 n-frags
#define M_BANK 30000
#define MP2    30208             // 472 * 64
#define NBLK   (MP2/64)          // 472 blocks, one 64-row bank tile each
#define KCN    12                // 384 / 32 k-chunks
#define IMGSZ  224
#define TOPK   9
#define SPLIT  32
#define RED1   59                // 472 = 8 * 59 reduce split

typedef __attribute__((ext_vector_type(8))) short short8v;   // bf16x8 bits (4 VGPR)
typedef __attribute__((ext_vector_type(4))) float f32x4;

// ---------------- bf16 split helpers ----------------
__device__ __forceinline__ ushort f2bf(float x) {
  union { float f; unsigned u; } a; a.f = x;
  const unsigned r = a.u + 0x7fffu + ((a.u >> 16) & 1u);   // RNE
  return (ushort)(r >> 16);
}
__device__ __forceinline__ float bf2f(ushort b) {
  union { float f; unsigned u; } a; a.u = ((unsigned)b) << 16;
  return a.f;
}

// ---------------- embedding build ----------------
__global__ __launch_bounds__(256) void pool2_kernel(const float* __restrict__ feat2,
                                                    float* __restrict__ embT) {
  const int bc = blockIdx.x;            // b*128+c
  const int b = bc >> 7, c = bc & 127;
  __shared__ float plane[H2*W2];
  const float* src = feat2 + (size_t)bc * (H2*W2);
  for (int i = threadIdx.x; i < H2*W2; i += 256) plane[i] = src[i];
  __syncthreads();
  for (int i = threadIdx.x; i < H2*W2; i += 256) {
    const int h = i / W2, w = i % W2;
    float s = 0.f;
    #pragma unroll
    for (int dh = -1; dh <= 1; ++dh)
      #pragma unroll
      for (int dw = -1; dw <= 1; ++dw) {
        const int hh = h + dh, ww = w + dw;
        if (hh >= 0 && hh < H2 && ww >= 0 && ww < W2) s += plane[hh*W2 + ww];
      }
    embT[(size_t)c * N_EMB + (size_t)b * (H2*W2) + i] = s * (1.0f/9.0f);
  }
}

__global__ __launch_bounds__(256) void pool3up_kernel(const float* __restrict__ feat3,
                                                      float* __restrict__ embT) {
  const int bc = blockIdx.x;            // b*256+c
  const int b = bc >> 8, c = bc & 255;
  __shared__ float plane[H3*W3];
  __shared__ float pooled[H3*W3];
  const float* src = feat3 + (size_t)bc * (H3*W3);
  for (int i = threadIdx.x; i < H3*W3; i += 256) plane[i] = src[i];
  __syncthreads();
  for (int i = threadIdx.x; i < H3*W3; i += 256) {
    const int h = i / W3, w = i % W3;
    float s = 0.f;
    #pragma unroll
    for (int dh = -1; dh <= 1; ++dh)
      #pragma unroll
      for (int dw = -1; dw <= 1; ++dw) {
        const int hh = h + dh, ww = w + dw;
        if (hh >= 0 && hh < H3 && ww >= 0 && ww < W3) s += plane[hh*W3 + ww];
      }
    pooled[i] = s * (1.0f/9.0f);
  }
  __syncthreads();
  for (int i = threadIdx.x; i < H2*W2; i += 256) {
    const int h = i / W2, w = i % W2;
    const float sy = h*0.5f - 0.25f, sx = w*0.5f - 0.25f;
    const int y0 = (int)floorf(sy), x0 = (int)floorf(sx);
    const float fy = sy - y0, fx = sx - x0;
    const int y0c = min(max(y0, 0), H3-1),   y1c = min(max(y0+1, 0), H3-1);
    const int x0c = min(max(x0, 0), W3-1),   x1c = min(max(x0+1, 0), W3-1);
    const float v =
        (1.f-fy)*((1.f-fx)*pooled[y0c*W3+x0c] + fx*pooled[y0c*W3+x1c]) +
             fy *((1.f-fx)*pooled[y1c*W3+x0c] + fx*pooled[y1c*W3+x1c]);
    embT[(size_t)(C2 + c) * N_EMB + (size_t)b * (H2*W2) + i] = v;
  }
}

// embT [C][N] f32 -> frag-major bf16 hi/lo. Frag (nf,kc): lane holds n=nf*16+(lane&15),
// k = kc*32+(lane>>4)*8+j. Storage: [((nf*12+kc)*64 + lane)*8 + j].
__global__ __launch_bounds__(256) void embconv_frag(const float* __restrict__ embT,
                                                    ushort* __restrict__ eh,
                                                    ushort* __restrict__ el) {
  const int id = blockIdx.x*256 + threadIdx.x;      // (nf*12+kc)*64 + lane
  const int lane = id & 63;
  const int fk = id >> 6;                           // nf*12+kc
  if (fk >= NFRAG*KCN) return;
  const int kc = fk % KCN, nf = fk / KCN;
  const int n = nf*16 + (lane & 15);
  const int c0 = kc*32 + (lane >> 4)*8;
  union { ushort u[8]; short8v v; } H, L;
  if (n < N_EMB) {
    #pragma unroll
    for (int j = 0; j < 8; ++j) {
      const float v = embT[(size_t)(c0 + j)*N_EMB + n];
      H.u[j] = f2bf(v); L.u[j] = f2bf(v - bf2f(H.u[j]));
    }
  } else {
    #pragma unroll
    for (int j = 0; j < 8; ++j) { H.u[j] = 0; L.u[j] = 0; }
  }
  *(short8v*)&eh[((size_t)fk << 9) + (lane << 3)] = H.v;
  *(short8v*)&el[((size_t)fk << 9) + (lane << 3)] = L.v;
}

// bank f32 [30000][384] -> frag-major per 64-row tile: [(((tile*4+mf)*12+kc)*64+lane)*8+j]
__global__ __launch_bounds__(256) void conv_bank_frag(const float* __restrict__ bank,
                                                      ushort* __restrict__ bh,
                                                      ushort* __restrict__ bl) {
  const int id = blockIdx.x*256 + threadIdx.x;      // m*48 + kq
  if (id >= MP2*48) return;
  const int kq = id % 48, m = id / 48;
  const int kc = kq >> 2;
  const int lane = (m & 15) + ((kq & 3) << 4);
  const int tile = m >> 6, mf = (m >> 4) & 3;
  union { ushort u[8]; short8v v; } H, L;
  if (m < M_BANK) {
    const float* src = bank + (size_t)m*CDIM + kq*8;
    #pragma unroll
    for (int j = 0; j < 8; ++j) {
      const float v = src[j];
      H.u[j] = f2bf(v); L.u[j] = f2bf(v - bf2f(H.u[j]));
    }
  } else {
    #pragma unroll
    for (int j = 0; j < 8; ++j) { H.u[j] = 0; L.u[j] = 0; }
  }
  const size_t dst = ((size_t)((tile*4 + mf)*KCN + kc) << 9) + (lane << 3);
  *(short8v*)&bh[dst] = H.v;
  *(short8v*)&bl[dst] = L.v;
}

// ---------------- norms ----------------
__global__ void xn_kernel(const float* __restrict__ embT, float* __restrict__ xn) {
  const int n = blockIdx.x*256 + threadIdx.x;
  if (n >= N_EMB) return;
  float s = 0.f;
  for (int c = 0; c < CDIM; ++c) {
    const float v = embT[(size_t)c * N_EMB + n];
    s = fmaf(v, v, s);
  }
  xn[n] = s;
}

__global__ void yn_kernel(const float* __restrict__ bank, float* __restrict__ yn) {
  const int wave = threadIdx.x >> 6, lane = threadIdx.x & 63;
  const int m = blockIdx.x*4 + wave;
  if (m >= MP2) return;
  if (m >= M_BANK) { if (lane == 0) yn[m] = 1e30f; return; }
  const float* row = bank + (size_t)m * CDIM;
  float s = 0.f;
  #pragma unroll
  for (int j = 0; j < CDIM/64; ++j) {
    const float v = row[lane + j*64];
    s = fmaf(v, v, s);
  }
  #pragma unroll
  for (int sh = 32; sh > 0; sh >>= 1) s += __shfl_down(s, sh);
  if (lane == 0) yn[m] = s;
}

// ---------------- fused distance GEMM (bf16-split MFMA) + min/argmin ----------------
// Block: 64-row bank tile frag-major in LDS (96 KB, staged once, ONE barrier).
// 8 waves x (64m x 64n) per nt step; 13 nt steps sweep all emb. Barrier-free main loop.
__global__ __launch_bounds__(512, 2) void distmin_mfma(
    const ushort* __restrict__ ehf, const ushort* __restrict__ elf,
    const ushort* __restrict__ bhf, const ushort* __restrict__ blf,
    const float* __restrict__ yn,
    float* __restrict__ pmin, int* __restrict__ parg)
{
  __shared__ ushort ash[24576];   // 48 frags x 512 ushorts (49152 B)
  __shared__ ushort asl[24576];

  const int tid = threadIdx.x;
  const int wave = tid >> 6, lane = tid & 63;
  const int lg = lane >> 4, lr = lane & 15;
  const int mbase = blockIdx.x * 64;

  // stage bank tile (contiguous, frag-major) -> LDS, coalesced 16B chunks
  {
    const ushort* sH = bhf + (size_t)blockIdx.x * 24576;
    const ushort* sL = blf + (size_t)blockIdx.x * 24576;
    for (int i = tid; i < 3072; i += 512) {
      *(short8v*)&ash[i << 3] = *(const short8v*)&sH[i << 3];
      *(short8v*)&asl[i << 3] = *(const short8v*)&sL[i << 3];
    }
  }
  __syncthreads();

  // per-lane yn for the 16 m-values this lane accumulates
  float yv[4][4];
  #pragma unroll
  for (int mf = 0; mf < 4; ++mf)
    #pragma unroll
    for (int r = 0; r < 4; ++r)
      yv[mf][r] = yn[mbase + mf*16 + lg*4 + r];

  for (int nt = 0; nt < NPAD/512; ++nt) {
    const int nc = nt*512 + wave*64;
    const int nf0 = nc >> 4;

    f32x4 acc[4][4];
    #pragma unroll
    for (int mf = 0; mf < 4; ++mf)
      #pragma unroll
      for (int t = 0; t < 4; ++t) acc[mf][t] = (f32x4){0.f, 0.f, 0.f, 0.f};

    #pragma unroll 4
    for (int kc = 0; kc < KCN; ++kc) {
      short8v ah[4], al[4], vbh[4], vbl[4];
      #pragma unroll
      for (int mf = 0; mf < 4; ++mf) {
        ah[mf] = *(const short8v*)&ash[((mf*KCN + kc) << 9) + (lane << 3)];
        al[mf] = *(const short8v*)&asl[((mf*KCN + kc) << 9) + (lane << 3)];
      }
      #pragma unroll
      for (int t = 0; t < 4; ++t) {
        const size_t fo = (((size_t)(nf0 + t)*KCN + kc) << 9) + (lane << 3);
        vbh[t] = *(const short8v*)&ehf[fo];
        vbl[t] = *(const short8v*)&elf[fo];
      }
      #pragma unroll
      for (int mf = 0; mf < 4; ++mf)
        #pragma unroll
        for (int t = 0; t < 4; ++t) {
          acc[mf][t] = __builtin_amdgcn_mfma_f32_16x16x32_bf16(ah[mf], vbh[t], acc[mf][t], 0, 0, 0);
          acc[mf][t] = __builtin_amdgcn_mfma_f32_16x16x32_bf16(ah[mf], vbl[t], acc[mf][t], 0, 0, 0);
          acc[mf][t] = __builtin_amdgcn_mfma_f32_16x16x32_bf16(al[mf], vbh[t], acc[mf][t], 0, 0, 0);
        }
    }

    // per n-col: min over this wave's 64 m (in-lane 16, then lanes xor16/32)
    #pragma unroll
    for (int t = 0; t < 4; ++t) {
      float bv = FLT_MAX; int bi = INT_MAX;
      #pragma unroll
      for (int mf = 0; mf < 4; ++mf)
        #pragma unroll
        for (int r = 0; r < 4; ++r) {
          const float d = yv[mf][r] - 2.0f*acc[mf][t][r];
          const int m = mbase + mf*16 + lg*4 + r;
          if (d < bv) { bv = d; bi = m; }        // ascending m -> first index kept
        }
      #pragma unroll
      for (int off = 16; off < 64; off <<= 1) {
        const float ov = __shfl_xor(bv, off);
        const int   oi = __shfl_xor(bi, off);
        if (ov < bv || (ov == bv && oi < bi)) { bv = ov; bi = oi; }
      }
      if (lg == 0) {
        const int n = nc + t*16 + lr;
        if (n < N_EMB) {
          pmin[(size_t)blockIdx.x*N_EMB + n] = bv;
          parg[(size_t)blockIdx.x*N_EMB + n] = bi;
        }
      }
    }
  }
}

// ---------------- two-stage partial-min reduce (472 -> 8 -> 1) ----------------
__global__ void reduce_stage1(const float* __restrict__ pmin, const int* __restrict__ parg,
                              float* __restrict__ pm2, int* __restrict__ pa2) {
  const int n = blockIdx.x*256 + threadIdx.x;
  if (n >= N_EMB) return;
  const int g = blockIdx.y;
  float bv = FLT_MAX; int bi = INT_MAX;
  for (int y = g*RED1; y < (g+1)*RED1; ++y) {
    const float v = pmin[(size_t)y*N_EMB + n];
    const int ix = parg[(size_t)y*N_EMB + n];
    if (v < bv || (v == bv && ix < bi)) { bv = v; bi = ix; }
  }
  pm2[(size_t)g*N_EMB + n] = bv;
  pa2[(size_t)g*N_EMB + n] = bi;
}

__global__ void reduce_stage2(const float* __restrict__ pm2, const int* __restrict__ pa2,
                              const float* __restrict__ xn,
                              float* __restrict__ pscore, int* __restrict__ ploc) {
  const int n = blockIdx.x*256 + threadIdx.x;
  if (n >= N_EMB) return;
  float bv = pm2[n]; int bi = pa2[n];
  #pragma unroll
  for (int g = 1; g < 8; ++g) {
    const float v = pm2[(size_t)g*N_EMB + n];
    const int ix = pa2[(size_t)g*N_EMB + n];
    if (v < bv || (v == bv && ix < bi)) { bv = v; bi = ix; }
  }
  pscore[n] = sqrtf(fmaxf(xn[n] + bv, 0.f));
  ploc[n] = bi;
}

// ---------------- per-batch argmax + gathers ----------------
__global__ __launch_bounds__(256) void perb_argmax(
    const float* __restrict__ pscore, const int* __restrict__ ploc,
    const float* __restrict__ embT,   const float* __restrict__ xn,
    float* __restrict__ scoreB, int* __restrict__ nnidx,
    float* __restrict__ maxfeat, float* __restrict__ mfnorm)
{
  const int b = blockIdx.x, tid = threadIdx.x;
  __shared__ float sv[256]; __shared__ int si[256];
  float bv = -FLT_MAX; int bi = INT_MAX;
  for (int p = tid; p < H2*W2; p += 256) {
    const float v = pscore[b*(H2*W2) + p];
    if (v > bv) { bv = v; bi = p; }
  }
  sv[tid] = bv; si[tid] = bi;
  __syncthreads();
  for (int s = 128; s > 0; s >>= 1) {
    if (tid < s) {
      if (sv[tid+s] > sv[tid] || (sv[tid+s] == sv[tid] && si[tid+s] < si[tid])) {
        sv[tid] = sv[tid+s]; si[tid] = si[tid+s];
      }
    }
    __syncthreads();
  }
  const int n = b*(H2*W2) + si[0];
  if (tid == 0) { scoreB[b] = sv[0]; nnidx[b] = ploc[n]; mfnorm[b] = xn[n]; }
  for (int c = tid; c < CDIM; c += 256) maxfeat[b*CDIM + c] = embT[(size_t)c*N_EMB + n];
}

// ---------------- per-batch 9-NN of nn_sample: 8 batches fused per segment ----------------
__global__ __launch_bounds__(512) void topk_partial(
    const float* __restrict__ bank, const float* __restrict__ yn,
    const int* __restrict__ nnidx, float* __restrict__ candv, int* __restrict__ candi)
{
  const int seg = blockIdx.x, tid = threadIdx.x;
  __shared__ float nnf[B_SZ*CDIM];        // 12 KB
  __shared__ float d2s[B_SZ][1024];       // 32 KB
  __shared__ float nrm[B_SZ];
  for (int i = tid; i < B_SZ*CDIM; i += 512) {
    const int b = i / CDIM, c = i % CDIM;
    nnf[i] = bank[(size_t)nnidx[b]*CDIM + c];
  }
  if (tid < B_SZ) nrm[tid] = yn[nnidx[tid]];
  __syncthreads();
  const int per = (M_BANK + SPLIT - 1) / SPLIT;   // 938
  const int mlo = seg * per;
  const int mhi = min(mlo + per, M_BANK);
  #pragma unroll
  for (int i = 0; i < 2; ++i) {
    const int p = i*512 + tid;
    const int m = mlo + p;
    if (m < mhi) {
      const float* row = bank + (size_t)m*CDIM;
      float dot[B_SZ];
      #pragma unroll
      for (int b = 0; b < B_SZ; ++b) dot[b] = 0.f;
      for (int c = 0; c < CDIM; c += 4) {
        const float4 r4 = *(const float4*)&row[c];
        #pragma unroll
        for (int b = 0; b < B_SZ; ++b) {
          dot[b] = fmaf(r4.x, nnf[b*CDIM+c+0], dot[b]);
          dot[b] = fmaf(r4.y, nnf[b*CDIM+c+1], dot[b]);
          dot[b] = fmaf(r4.z, nnf[b*CDIM+c+2], dot[b]);
          dot[b] = fmaf(r4.w, nnf[b*CDIM+c+3], dot[b]);
        }
      }
      const float ym = yn[m];
      #pragma unroll
      for (int b = 0; b < B_SZ; ++b) d2s[b][p] = nrm[b] - 2.f*dot[b] + ym;
    } else {
      #pragma unroll
      for (int b = 0; b < B_SZ; ++b) d2s[b][p] = FLT_MAX;
    }
  }
  __syncthreads();
  const int b = tid >> 6, lane = tid & 63;
  for (int r = 0; r < TOPK; ++r) {
    float bv = FLT_MAX; int bp = INT_MAX;
    #pragma unroll
    for (int s = 0; s < 16; ++s) {
      const int p = lane + s*64;
      const float v = d2s[b][p];
      if (v < bv || (v == bv && p < bp)) { bv = v; bp = p; }
    }
    #pragma unroll
    for (int off = 32; off > 0; off >>= 1) {
      const float ov = __shfl_down(bv, off);
      const int   op = __shfl_down(bp, off);
      if (ov < bv || (ov == bv && op < bp)) { bv = ov; bp = op; }
    }
    if (lane == 0) {
      candv[((size_t)b*SPLIT + seg)*TOPK + r] = bv;
      candi[((size_t)b*SPLIT + seg)*TOPK + r] = mlo + bp;
      d2s[b][bp] = FLT_MAX;
    }
    __syncthreads();
  }
}

// ---------------- merge candidates, compute pred_score ----------------
__global__ __launch_bounds__(320) void final_score(
    const float* __restrict__ bank, const float* __restrict__ yn,
    const float* __restrict__ candv, const int* __restrict__ candi,
    const float* __restrict__ maxfeat, const float* __restrict__ mfnorm,
    const float* __restrict__ scoreB, float* __restrict__ outp)
{
  const int b = blockIdx.x, tid = threadIdx.x;
  __shared__ float av[SPLIT*TOPK]; __shared__ int ai[SPLIT*TOPK];
  __shared__ int sup[TOPK];
  __shared__ float dist2[TOPK];
  if (tid < SPLIT*TOPK) {
    av[tid] = candv[(size_t)b*SPLIT*TOPK + tid];
    ai[tid] = candi[(size_t)b*SPLIT*TOPK + tid];
  }
  __syncthreads();
  if (tid == 0) {
    for (int r = 0; r < TOPK; ++r) {
      float bv = FLT_MAX; int bi = INT_MAX; int bp = -1;
      for (int p = 0; p < SPLIT*TOPK; ++p) {
        if (av[p] < bv || (av[p] == bv && ai[p] < bi)) { bv = av[p]; bi = ai[p]; bp = p; }
      }
      sup[r] = bi; av[bp] = FLT_MAX;
    }
  }
  __syncthreads();
  if (tid < TOPK*32) {
    const int j = tid >> 5, l = tid & 31;
    const float* row = bank + (size_t)sup[j]*CDIM;
    const float* mf  = maxfeat + b*CDIM;
    float p = 0.f;
    for (int c = l; c < CDIM; c += 32) p = fmaf(row[c], mf[c], p);
    #pragma unroll
    for (int s = 16; s > 0; s >>= 1) p += __shfl_down(p, s, 32);
    if (l == 0) dist2[j] = mfnorm[b] - 2.f*p + yn[sup[j]];
  }
  __syncthreads();
  if (tid == 0) {
    const float sc = scoreB[b];
    float se = 0.f;
    for (int j = 0; j < TOPK; ++j) se += expf(sqrtf(fmaxf(dist2[j], 0.f)));
    outp[b] = (1.f - expf(sc)/se) * sc;
  }
}

// ---------------- anomaly map: 28->224 bilinear then 33-tap separable gaussian ----------------
__global__ void resize_kernel(const float* __restrict__ pscore, float* __restrict__ amap) {
  const int idx = blockIdx.x*256 + threadIdx.x;
  if (idx >= B_SZ*IMGSZ*IMGSZ) return;
  const int b = idx / (IMGSZ*IMGSZ);
  const int r = idx % (IMGSZ*IMGSZ);
  const int oy = r / IMGSZ, ox = r % IMGSZ;
  const float sy = oy*0.125f - 0.4375f, sx = ox*0.125f - 0.4375f;
  const int y0 = (int)floorf(sy), x0 = (int)floorf(sx);
  const float fy = sy - y0, fx = sx - x0;
  const int y0c = min(max(y0, 0), H2-1), y1c = min(max(y0+1, 0), H2-1);
  const int x0c = min(max(x0, 0), W2-1), x1c = min(max(x0+1, 0), W2-1);
  const float* p = pscore + b*(H2*W2);
  amap[idx] = (1.f-fy)*((1.f-fx)*p[y0c*W2+x0c] + fx*p[y0c*W2+x1c]) +
                   fy *((1.f-fx)*p[y1c*W2+x0c] + fx*p[y1c*W2+x1c]);
}

__device__ __forceinline__ void make_gauss(float* kr, float* kinv, int tid) {
  if (tid < 33) { const float x = (tid - 16) * 0.25f; kr[tid] = expf(-0.5f*x*x); }
  __syncthreads();
  if (tid == 0) { float s = 0.f; for (int i = 0; i < 33; ++i) s += kr[i]; *kinv = 1.0f/s; }
  __syncthreads();
}

__global__ __launch_bounds__(256) void blurh_kernel(const float* __restrict__ amap,
                                                    float* __restrict__ tmp) {
  __shared__ float kr[33]; __shared__ float kinv; __shared__ float row[256];
  const int tid = threadIdx.x;
  make_gauss(kr, &kinv, tid);
  const int b = blockIdx.x / IMGSZ, y = blockIdx.x % IMGSZ;
  const float* src = amap + (size_t)(b*IMGSZ + y)*IMGSZ;
  const int xx = tid - 16;
  row[tid] = (xx >= 0 && xx < IMGSZ) ? src[xx] : 0.f;
  __syncthreads();
  if (tid < IMGSZ) {
    float s = 0.f;
    #pragma unroll
    for (int j = 0; j < 33; ++j) s = fmaf(kr[j], row[tid + j], s);
    tmp[(size_t)(b*IMGSZ + y)*IMGSZ + tid] = s * kinv;
  }
}

__global__ __launch_bounds__(256) void blurv_kernel(const float* __restrict__ tmp,
                                                    float* __restrict__ outp) {
  __shared__ float kr[33]; __shared__ float kinv;
  const int tid = threadIdx.x;
  make_gauss(kr, &kinv, tid);
  const int b = blockIdx.x / IMGSZ, y = blockIdx.x % IMGSZ;
  if (tid < IMGSZ) {
    float s = 0.f;
    #pragma unroll
    for (int j = 0; j < 33; ++j) {
      const int yy = y + j - 16;
      if (yy >= 0 && yy < IMGSZ) s = fmaf(kr[j], tmp[(size_t)(b*IMGSZ + yy)*IMGSZ + tid], s);
    }
    outp[(size_t)(b*IMGSZ + y)*IMGSZ + tid] = s * kinv;
  }
}

// ---------------- launch ----------------
extern "C" void kernel_launch(void* const* d_in, const int* in_sizes, int n_in,
                              void* d_out, int out_size, void* d_ws, size_t ws_size,
                              hipStream_t stream) {
  (void)in_sizes; (void)n_in; (void)out_size; (void)ws_size;
  const float* feat2 = (const float*)d_in[0];
  const float* feat3 = (const float*)d_in[1];
  const float* bank  = (const float*)d_in[2];
  float* out = (float*)d_out;

  char* w = (char*)d_ws;
  size_t off = 0;
  auto take = [&](size_t bytes) -> void* {
    void* p = w + off;
    off = (off + bytes + 255) & ~(size_t)255;
    return p;
  };
  float*  embT    = (float*) take(sizeof(float)*(size_t)CDIM*N_EMB);        // 9.6 MB
  ushort* ehf     = (ushort*)take(sizeof(ushort)*(size_t)NFRAG*KCN*512);    // 5.1 MB
  ushort* elf     = (ushort*)take(sizeof(ushort)*(size_t)NFRAG*KCN*512);
  ushort* bhf     = (ushort*)take(sizeof(ushort)*(size_t)NBLK*24576);      // 23.2 MB
  ushort* blf     = (ushort*)take(sizeof(ushort)*(size_t)NBLK*24576);
  float*  xn      = (float*) take(sizeof(float)*N_EMB);
  float*  yn      = (float*) take(sizeof(float)*MP2);
  float*  pmin    = (float*) take(sizeof(float)*(size_t)NBLK*N_EMB);       // 11.8 MB
  int*    parg    = (int*)   take(sizeof(int)*(size_t)NBLK*N_EMB);         // 11.8 MB
  float*  pm2     = (float*) take(sizeof(float)*8*N_EMB);
  int*    pa2     = (int*)   take(sizeof(int)*8*N_EMB);
  float*  pscore  = (float*) take(sizeof(float)*N_EMB);
  int*    ploc    = (int*)   take(sizeof(int)*N_EMB);
  float*  scoreB  = (float*) take(sizeof(float)*B_SZ);
  int*    nnidx   = (int*)   take(sizeof(int)*B_SZ);
  float*  mfnorm  = (float*) take(sizeof(float)*B_SZ);
  float*  maxfeat = (float*) take(sizeof(float)*B_SZ*CDIM);
  float*  candv   = (float*) take(sizeof(float)*B_SZ*SPLIT*TOPK);
  int*    candi   = (int*)   take(sizeof(int)*B_SZ*SPLIT*TOPK);
  float*  amap    = (float*) take(sizeof(float)*(size_t)B_SZ*IMGSZ*IMGSZ);
  float*  tmpb    = (float*) take(sizeof(float)*(size_t)B_SZ*IMGSZ*IMGSZ);

  // embedding f32 [C][N] + frag-major bf16-split operands
  hipLaunchKernelGGL(pool2_kernel,   dim3(B_SZ*C2), dim3(256), 0, stream, feat2, embT);
  hipLaunchKernelGGL(pool3up_kernel, dim3(B_SZ*C3), dim3(256), 0, stream, feat3, embT);
  hipLaunchKernelGGL(embconv_frag, dim3((NFRAG*KCN*64 + 255)/256), dim3(256), 0, stream,
                     embT, ehf, elf);
  hipLaunchKernelGGL(conv_bank_frag, dim3(MP2*48/256), dim3(256), 0, stream, bank, bhf, blf);
  hipLaunchKernelGGL(xn_kernel, dim3((N_EMB+255)/256), dim3(256), 0, stream, embT, xn);
  hipLaunchKernelGGL(yn_kernel, dim3(MP2/4), dim3(256), 0, stream, bank, yn);

  // fused distance GEMM: bank tile in LDS (frag-major), emb streamed coalesced from L2
  hipLaunchKernelGGL(distmin_mfma, dim3(NBLK), dim3(512), 0, stream,
                     ehf, elf, bhf, blf, yn, pmin, parg);
  hipLaunchKernelGGL(reduce_stage1, dim3((N_EMB+255)/256, 8), dim3(256), 0, stream,
                     pmin, parg, pm2, pa2);
  hipLaunchKernelGGL(reduce_stage2, dim3((N_EMB+255)/256), dim3(256), 0, stream,
                     pm2, pa2, xn, pscore, ploc);

  // pred_score path (exact f32)
  hipLaunchKernelGGL(perb_argmax, dim3(B_SZ), dim3(256), 0, stream,
                     pscore, ploc, embT, xn, scoreB, nnidx, maxfeat, mfnorm);
  hipLaunchKernelGGL(topk_partial, dim3(SPLIT), dim3(512), 0, stream,
                     bank, yn, nnidx, candv, candi);
  hipLaunchKernelGGL(final_score, dim3(B_SZ), dim3(320), 0, stream,
                     bank, yn, candv, candi, maxfeat, mfnorm, scoreB, out);

  // anomaly map path
  hipLaunchKernelGGL(resize_kernel, dim3((B_SZ*IMGSZ*IMGSZ+255)/256), dim3(256), 0, stream,
                     pscore, amap);
  hipLaunchKernelGGL(blurh_kernel, dim3(B_SZ*IMGSZ), dim3(256), 0, stream, amap, tmpb);
  hipLaunchKernelGGL(blurv_kernel, dim3(B_SZ*IMGSZ), dim3(256), 0, stream, tmpb, out + B_SZ);
}